// Round 8
// baseline (122.762 us; speedup 1.0000x reference)
//
#include <hip/hip_runtime.h>

#define NN 192
#define BZ 4
#define YC 8
#define NTHR 256
#define ROWF 192                    // floats per staged row (full x line)
#define ROWS 12                     // 6 I rows + 6 J rows per plane
#define BUF_F (ROWS * ROWF)         // 2304 floats per plane buffer

// x mapped across the 64 lanes of a wave, 3 floats/lane (192 = 64*3).
// z-fold-first: fold the z-triple into p = z-box, q = z-diff per (x,y); then
//   Gx = S(x+1)-S(x-1),      S = y-box of p
//   Gy = D(x-1)+D(x)+D(x+1), D = y-diff of p
//   Gz = T(x-1)+T(x)+T(x+1), T = y-box of q
// x-halo of p/q from neighbor lanes via shuffle, kept in 5-wide slots.
// Raw (un-halved) gradients: 0.5^2 factors cancel when EPS^2 -> 4*EPS^2 = 0.04.
//
// Staging: per y-step one plane (12 z-shared rows x 192 floats: I rows
// z0-1..z0+4 then J rows) goes global->regs (issued one step early) ->
// ds_write_b96 -> double-buffered LDS. One barrier per step. Each wave
// stages 3 rows and reads its 6 (z-1,z,z+1 for I and J).

__device__ __forceinline__ void fold_pq(const float3 rm, const float3 r0, const float3 rp,
                                        int lane, float pe[5], float qe[5]) {
    const float p0 = rm.x + r0.x + rp.x;
    const float p1 = rm.y + r0.y + rp.y;
    const float p2 = rm.z + r0.z + rp.z;
    const float q0 = rp.x - rm.x;
    const float q1 = rp.y - rm.y;
    const float q2 = rp.z - rm.z;
    float pL = __shfl_up(p2, 1, 64);
    float pR = __shfl_down(p0, 1, 64);
    float qL = __shfl_up(q2, 1, 64);
    float qR = __shfl_down(q0, 1, 64);
    if (lane == 0)  { pL = p0; qL = q0; }   // clamp x=-1 -> 0
    if (lane == 63) { pR = p2; qR = q2; }   // clamp x=192 -> 191
    pe[0] = pL; pe[1] = p0; pe[2] = p1; pe[3] = p2; pe[4] = pR;
    qe[0] = qL; qe[1] = q0; qe[2] = q1; qe[3] = q2; qe[4] = qR;
}

__global__ __launch_bounds__(NTHR, 4) void ngf_kernel(const float* __restrict__ I,
                                                      const float* __restrict__ J,
                                                      const float* __restrict__ M,
                                                      float* __restrict__ out) {
    __shared__ float sbuf[2 * BUF_F];      // 18432 B
    __shared__ float red[NTHR / 64];

    const int lane = threadIdx.x;          // 0..63
    const int tz = threadIdx.y;            // wave id / z within tile
    const int z0 = blockIdx.y * BZ;
    const int z = z0 + tz;
    const int ybase = blockIdx.x * YC;

    // ---- staging assignment: wave tz stages plane rows rr = 3*tz + j
    const float* srow[3];                  // per-lane global base (y=0)
    int loff[3];                           // LDS float offset (incl. lane)
#pragma unroll
    for (int j = 0; j < 3; ++j) {
        const int rr = tz * 3 + j;         // 0..11
        const int arr = rr / 6;            // 0 = I, 1 = J
        const int zr = rr - arr * 6;       // 0..5 -> z = z0-1+zr
        int zc = z0 - 1 + zr;
        zc = zc < 0 ? 0 : (zc > NN - 1 ? NN - 1 : zc);
        srow[j] = (arr ? J : I) + zc * NN * NN + lane * 3;
        loff[j] = rr * ROWF + lane * 3;
    }
    const float* mbase = M + z * NN * NN + lane * 3;

    float pe[2][3][5], qe[2][3][5];        // rotating slots [array][slot][5]
    float3 R[3];                           // staging registers

    // ---- pre-iter A: plane clamp(ybase-1) -> buf0 -> slot0
    {
        const int gy = (ybase == 0) ? 0 : (ybase - 1);
#pragma unroll
        for (int j = 0; j < 3; ++j) R[j] = *(const float3*)(srow[j] + gy * NN);
#pragma unroll
        for (int j = 0; j < 3; ++j) *(float3*)&sbuf[0 * BUF_F + loff[j]] = R[j];
        __syncthreads();
#pragma unroll
        for (int ar = 0; ar < 2; ++ar) {
            const float* bb = sbuf + 0 * BUF_F + (ar * 6 + tz) * ROWF + lane * 3;
            fold_pq(*(const float3*)(bb), *(const float3*)(bb + ROWF),
                    *(const float3*)(bb + 2 * ROWF), lane, pe[ar][0], qe[ar][0]);
        }
    }
    // ---- pre-iter B: plane ybase -> buf1 -> slot1
    {
#pragma unroll
        for (int j = 0; j < 3; ++j) R[j] = *(const float3*)(srow[j] + ybase * NN);
#pragma unroll
        for (int j = 0; j < 3; ++j) *(float3*)&sbuf[1 * BUF_F + loff[j]] = R[j];
        __syncthreads();
#pragma unroll
        for (int ar = 0; ar < 2; ++ar) {
            const float* bb = sbuf + 1 * BUF_F + (ar * 6 + tz) * ROWF + lane * 3;
            fold_pq(*(const float3*)(bb), *(const float3*)(bb + ROWF),
                    *(const float3*)(bb + 2 * ROWF), lane, pe[ar][1], qe[ar][1]);
        }
    }
    // preload plane ybase+1 (<= 185, no clamp needed) and mask(ybase)
#pragma unroll
    for (int j = 0; j < 3; ++j) R[j] = *(const float3*)(srow[j] + (ybase + 1) * NN);
    float3 mcur = *(const float3*)(mbase + ybase * NN);

    float acc = 0.0f;
#pragma unroll
    for (int yy = 0; yy < YC; ++yy) {
        const int bw = yy & 1;             // buffer for plane ybase+yy+1
        const int sC = (yy + 2) % 3;       // its slot
        const int s0 = yy % 3, s1 = (yy + 1) % 3;

        // commit plane ybase+yy+1 (loads issued one step ago)
#pragma unroll
        for (int j = 0; j < 3; ++j) *(float3*)&sbuf[bw * BUF_F + loff[j]] = R[j];
        __syncthreads();

        // issue next plane's loads + next mask (consumed next iteration)
        float3 mnxt = mcur;
        if (yy < YC - 1) {
            int gy = ybase + yy + 2;
            gy = (gy > NN - 1) ? (NN - 1) : gy;
#pragma unroll
            for (int j = 0; j < 3; ++j) R[j] = *(const float3*)(srow[j] + gy * NN);
            mnxt = *(const float3*)(mbase + (ybase + yy + 1) * NN);
        }

        // fold plane ybase+yy+1 from buf[bw] -> slot sC
#pragma unroll
        for (int ar = 0; ar < 2; ++ar) {
            const float* bb = sbuf + bw * BUF_F + (ar * 6 + tz) * ROWF + lane * 3;
            fold_pq(*(const float3*)(bb), *(const float3*)(bb + ROWF),
                    *(const float3*)(bb + 2 * ROWF), lane, pe[ar][sC], qe[ar][sC]);
        }

        // NGF at y = ybase+yy (slots s0=y-1, s1=y, sC=y+1)
        float G[2][3][3];
#pragma unroll
        for (int ar = 0; ar < 2; ++ar) {
            float S[5], D[5], T[5];
#pragma unroll
            for (int i = 0; i < 5; ++i) {
                S[i] = pe[ar][s0][i] + pe[ar][s1][i] + pe[ar][sC][i];
                D[i] = pe[ar][sC][i] - pe[ar][s0][i];
                T[i] = qe[ar][s0][i] + qe[ar][s1][i] + qe[ar][sC][i];
            }
#pragma unroll
            for (int i = 0; i < 3; ++i) {
                G[ar][0][i] = S[i + 2] - S[i];
                G[ar][1][i] = D[i] + D[i + 1] + D[i + 2];
                G[ar][2][i] = T[i] + T[i + 1] + T[i + 2];
            }
        }
        const float mm[3] = {mcur.x, mcur.y, mcur.z};
#pragma unroll
        for (int i = 0; i < 3; ++i) {
            const float Ix = G[0][0][i], Iy = G[0][1][i], Iz = G[0][2][i];
            const float Jx = G[1][0][i], Jy = G[1][1][i], Jz = G[1][2][i];
            const float im = Ix * Ix + Iy * Iy + Iz * Iz + 0.04f;
            const float jm = Jx * Jx + Jy * Jy + Jz * Jz + 0.04f;
            const float dot = Ix * Jx + Iy * Jy + Iz * Jz;
            acc += (1.0f - dot * dot * __builtin_amdgcn_rcpf(im * jm)) * mm[i];
        }
        mcur = mnxt;
    }

    // mean scaling, then wave -> block -> global reduction
    acc *= (1.0f / ((float)NN * (float)NN * (float)NN));
#pragma unroll
    for (int off = 32; off > 0; off >>= 1)
        acc += __shfl_down(acc, off, 64);

    if (lane == 0) red[tz] = acc;
    __syncthreads();
    if (tz == 0 && lane == 0) {
        float s = 0.0f;
#pragma unroll
        for (int w = 0; w < NTHR / 64; ++w) s += red[w];
        atomicAdd(out, s);
    }
}

extern "C" void kernel_launch(void* const* d_in, const int* in_sizes, int n_in,
                              void* d_out, int out_size, void* d_ws, size_t ws_size,
                              hipStream_t stream) {
    const float* I = (const float*)d_in[0];
    const float* J = (const float*)d_in[1];
    const float* M = (const float*)d_in[2];
    float* out = (float*)d_out;

    hipMemsetAsync(d_out, 0, sizeof(float), stream);

    dim3 block(64, BZ);               // 256 threads = 4 waves
    dim3 grid(NN / YC, NN / BZ);      // (24, 48) = 1152 blocks
    ngf_kernel<<<grid, block, 0, stream>>>(I, J, M, out);
}